// Round 10
// baseline (669.253 us; speedup 1.0000x reference)
//
#include <hip/hip_runtime.h>
#include <math.h>

#define HWn 16384
#define Hn  128
#define Wn  128
#define Bn  2
#define Cn  96
#define En  192
#define Gn  24
#define HEADn 16
#define CCn 12
#define Nn  12
#define HDn 384

// ---------------------------------------------------------------------------
// K1 v2: channel LayerNorm (eps 1e-6) + grouped 1x1 in-projection.
// 64-px tiles, 256 threads, grid (512, 2). LDS ~34.7 KB -> 4 blocks/CU.
// zn row stride 68 (16B-aligned, conflict-spread).
// ---------------------------------------------------------------------------
#define ZS 68

__global__ __launch_bounds__(256, 4) void k_ln_inproj(
    const float* __restrict__ x0, const float* __restrict__ x1,
    const float* __restrict__ lw0, const float* __restrict__ lb0,
    const float* __restrict__ lw1, const float* __restrict__ lb1,
    const float* __restrict__ pw0, const float* __restrict__ pw1,
    float* __restrict__ xr, float* __restrict__ v)
{
  __shared__ __align__(16) float zn[Cn * ZS];   // 26112 B
  __shared__ float red[2 * 16 * 64];            // 8192 B
  __shared__ float mus[64], rss[64];

  const int s    = blockIdx.y;
  const int tile = blockIdx.x;                  // 0..511
  const int b  = (tile * 64) >> 14;
  const int l0 = (tile * 64) & (HWn - 1);
  const int tid = threadIdx.x;

  const float* x  = s ? x1  : x0;
  const float* lw = s ? lw1 : lw0;
  const float* lb = s ? lb1 : lb0;
  const float* pw = s ? pw1 : pw0;

  const int px4 = (tid & 15) * 4;               // pixel base (float4)
  const int cg0 = tid >> 4;                     // channel start, step 16

  // ---- load tile (float4) + per-px partial stats ----
  const float* xp = x + (size_t)b * Cn * HWn + l0;
  float ps0=0.f,ps1=0.f,ps2=0.f,ps3=0.f, pq0=0.f,pq1=0.f,pq2=0.f,pq3=0.f;
#pragma unroll
  for (int i = 0; i < 6; ++i) {
    int ch = cg0 + 16 * i;
    float4 t = *(const float4*)&xp[(size_t)ch * HWn + px4];
    *(float4*)&zn[ch * ZS + px4] = t;
    ps0 += t.x; pq0 += t.x * t.x;
    ps1 += t.y; pq1 += t.y * t.y;
    ps2 += t.z; pq2 += t.z * t.z;
    ps3 += t.w; pq3 += t.w * t.w;
  }
  red[cg0 * 64 + px4 + 0] = ps0; red[1024 + cg0 * 64 + px4 + 0] = pq0;
  red[cg0 * 64 + px4 + 1] = ps1; red[1024 + cg0 * 64 + px4 + 1] = pq1;
  red[cg0 * 64 + px4 + 2] = ps2; red[1024 + cg0 * 64 + px4 + 2] = pq2;
  red[cg0 * 64 + px4 + 3] = ps3; red[1024 + cg0 * 64 + px4 + 3] = pq3;
  __syncthreads();
  if (tid < 64) {
    float sm = 0.f, sq = 0.f;
#pragma unroll
    for (int g = 0; g < 16; ++g) { sm += red[g * 64 + tid]; sq += red[1024 + g * 64 + tid]; }
    float mu = sm * (1.f / Cn);
    float var = sq * (1.f / Cn) - mu * mu;
    mus[tid] = mu; rss[tid] = rsqrtf(var + 1e-6f);
  }
  __syncthreads();

  // ---- normalize in LDS + write xr (float4) ----
  const float m0 = mus[px4+0], m1 = mus[px4+1], m2 = mus[px4+2], m3 = mus[px4+3];
  const float r0 = rss[px4+0], r1 = rss[px4+1], r2 = rss[px4+2], r3 = rss[px4+3];
  float* xrp = xr + ((size_t)s * Bn + b) * Cn * HWn + l0;
#pragma unroll
  for (int i = 0; i < 6; ++i) {
    int ch = cg0 + 16 * i;
    float4 t = *(const float4*)&zn[ch * ZS + px4];
    float wch = lw[ch], bch = lb[ch];
    t.x = fmaf((t.x - m0) * r0, wch, bch);
    t.y = fmaf((t.y - m1) * r1, wch, bch);
    t.z = fmaf((t.z - m2) * r2, wch, bch);
    t.w = fmaf((t.w - m3) * r3, wch, bch);
    *(float4*)&zn[ch * ZS + px4] = t;
    *(float4*)&xrp[(size_t)ch * HWn + px4] = t;
  }
  __syncthreads();

  // ---- inproj: thread = 12 outputs x 4 px; each output needs only 4 inputs ----
  const int og  = (tid >> 4) * 12;
  const int pxg = (tid & 15) * 4;
  float* vp = v + ((size_t)s * Bn + b) * En * HWn + l0;
#pragma unroll
  for (int jo = 0; jo < 12; ++jo) {
    int o = og + jo, g = o >> 3;
    float4 wv = *(const float4*)&pw[g * 32 + (o & 7) * 4];
    float4 z0 = *(const float4*)&zn[(g * 4 + 0) * ZS + pxg];
    float4 z1 = *(const float4*)&zn[(g * 4 + 1) * ZS + pxg];
    float4 z2 = *(const float4*)&zn[(g * 4 + 2) * ZS + pxg];
    float4 z3 = *(const float4*)&zn[(g * 4 + 3) * ZS + pxg];
    float4 a;
    a.x = fmaf(z0.x, wv.x, fmaf(z1.x, wv.y, fmaf(z2.x, wv.z, z3.x * wv.w)));
    a.y = fmaf(z0.y, wv.x, fmaf(z1.y, wv.y, fmaf(z2.y, wv.z, z3.y * wv.w)));
    a.z = fmaf(z0.z, wv.x, fmaf(z1.z, wv.y, fmaf(z2.z, wv.z, z3.z * wv.w)));
    a.w = fmaf(z0.w, wv.x, fmaf(z1.w, wv.y, fmaf(z2.w, wv.z, z3.w * wv.w)));
    *(float4*)&vp[(size_t)o * HWn + pxg] = a;
  }
}

// ---------------------------------------------------------------------------
// K2: depthwise 3x3 conv + bias + SiLU. grid (64, 192, 4)  (unchanged)
// ---------------------------------------------------------------------------
__global__ __launch_bounds__(256) void k_dwconv_silu(
    const float* __restrict__ v,
    const float* __restrict__ cw0, const float* __restrict__ cb0,
    const float* __restrict__ cw1, const float* __restrict__ cb1,
    float* __restrict__ u)
{
  const int z = blockIdx.z;                 // s*2+b
  const int e = blockIdx.y;
  const int p = blockIdx.x * 256 + threadIdx.x;
  const int h = p >> 7, w = p & 127;
  const int s = z >> 1;
  const float* cw  = (s ? cw1 : cw0) + e * 9;
  const float bias = (s ? cb1 : cb0)[e];
  const float* src = v + ((size_t)z * En + e) * HWn;

  float acc = bias;
#pragma unroll
  for (int kh = 0; kh < 3; ++kh) {
    int hh = h + kh - 1;
    if (hh < 0 || hh >= Hn) continue;
#pragma unroll
    for (int kw = 0; kw < 3; ++kw) {
      int ww = w + kw - 1;
      if (ww < 0 || ww >= Wn) continue;
      acc = fmaf(src[hh * Wn + ww], cw[kh * 3 + kw], acc);
    }
  }
  float sig = 1.f / (1.f + expf(-acc));
  u[((size_t)z * En + e) * HWn + p] = acc * sig;
}

// ---------------------------------------------------------------------------
// K3: SSM core, conflict-free LDS edition. (unchanged from round 6)
// ---------------------------------------------------------------------------
#define UPXS 417
#define USS  208
#define UDS  13
#define XPXS 604
#define XSS  300

__global__ __launch_bounds__(512) void k_ssm(
    const float* __restrict__ u_ws, const float* __restrict__ xr_ws,
    float* __restrict__ z_ws,
    const float* __restrict__ xprojw, const float* __restrict__ dtprojw,
    const float* __restrict__ dtprojb, const float* __restrict__ A_logs,
    const float* __restrict__ Ds,
    const float* __restrict__ on1w, const float* __restrict__ on1b,
    const float* __restrict__ on2w, const float* __restrict__ on2b,
    const float* __restrict__ opw0, const float* __restrict__ opw1)
{
  __shared__ __align__(16) float uS[16 * UPXS];    // 6672 f = 26688 B
  __shared__ __align__(16) float xdl[16 * XPXS];   // 9664 f = 38656 B

  const int tid  = threadIdx.x;
  const int tile = blockIdx.x;
  const int b  = (tile * 16) >> 14;
  const int l0 = (tile * 16) & (HWn - 1);

  const int p2px = tid >> 5, p2s = (tid >> 4) & 1, p2d = tid & 15;
  const float dtw = dtprojw[p2s * HEADn + p2d];
  const float dtb = dtprojb[p2s * HEADn + p2d];
  const float Dv  = Ds[p2s * HEADn + p2d];
  float Ar[Nn];
  {
    const float4* ap = (const float4*)&A_logs[(p2s * HEADn + p2d) * Nn];
    float4 a0 = ap[0], a1 = ap[1], a2 = ap[2];
    Ar[0]=-expf(a0.x); Ar[1]=-expf(a0.y); Ar[2]=-expf(a0.z); Ar[3]=-expf(a0.w);
    Ar[4]=-expf(a1.x); Ar[5]=-expf(a1.y); Ar[6]=-expf(a1.z); Ar[7]=-expf(a1.w);
    Ar[8]=-expf(a2.x); Ar[9]=-expf(a2.y); Ar[10]=-expf(a2.z); Ar[11]=-expf(a2.w);
  }

#pragma unroll
  for (int i = 0; i < 3; ++i) {
    int id = i * 512 + tid;
    int px4 = id & 3, rest = id >> 2;
    int ch = rest % En, s2 = rest / En;
    float4 t = *(const float4*)&u_ws[(((size_t)s2 * Bn + b) * En + ch) * HWn + l0 + px4 * 4];
    int dd = ch / 12, cc = ch % 12;
    int base = s2 * USS + dd * UDS + cc;
    uS[(px4 * 4 + 0) * UPXS + base] = t.x;
    uS[(px4 * 4 + 1) * UPXS + base] = t.y;
    uS[(px4 * 4 + 2) * UPXS + base] = t.z;
    uS[(px4 * 4 + 3) * UPXS + base] = t.w;
  }
  __syncthreads();

#pragma unroll
  for (int j = 0; j < 2; ++j) {
    int id = j * 512 + tid;
    if (id < 800) {
      int px = id & 15, sr = id >> 4;
      int s2 = sr / 25, r = sr % 25;
      const float4* xw4 = (const float4*)&xprojw[(s2 * 25 + r) * HEADn];
      float4 w0 = xw4[0], w1 = xw4[1], w2 = xw4[2], w3 = xw4[3];
      float wv[16];
      wv[0]=w0.x; wv[1]=w0.y; wv[2]=w0.z; wv[3]=w0.w;
      wv[4]=w1.x; wv[5]=w1.y; wv[6]=w1.z; wv[7]=w1.w;
      wv[8]=w2.x; wv[9]=w2.y; wv[10]=w2.z; wv[11]=w2.w;
      wv[12]=w3.x; wv[13]=w3.y; wv[14]=w3.z; wv[15]=w3.w;
      int ub = px * UPXS + s2 * USS;
      float acc[12];
#pragma unroll
      for (int cc = 0; cc < 12; ++cc) acc[cc] = 0.f;
#pragma unroll
      for (int dd = 0; dd < HEADn; ++dd) {
        float w = wv[dd];
        int ua = ub + dd * UDS;
#pragma unroll
        for (int cc = 0; cc < 12; ++cc)
          acc[cc] = fmaf(uS[ua + cc], w, acc[cc]);
      }
      float* xp = &xdl[px * XPXS + s2 * XSS + r * 12];
      *(float4*)&xp[0] = make_float4(acc[0], acc[1], acc[2], acc[3]);
      *(float4*)&xp[4] = make_float4(acc[4], acc[5], acc[6], acc[7]);
      *(float4*)&xp[8] = make_float4(acc[8], acc[9], acc[10], acc[11]);
    }
  }
  __syncthreads();

  {
    const int px = p2px, s = p2s, d = p2d;
    const int ub = px * UPXS + s * USS + d * UDS;
    float uvv[12];
#pragma unroll
    for (int cc = 0; cc < 12; ++cc) uvv[cc] = uS[ub + cc];

    const int xb = px * XPXS;
    float dts[12];
    {
      const float4* dr = (const float4*)&xdl[xb + s * XSS];   // r = 0
      float4 q0 = dr[0], q1 = dr[1], q2 = dr[2];
      dts[0]=q0.x; dts[1]=q0.y; dts[2]=q0.z; dts[3]=q0.w;
      dts[4]=q1.x; dts[5]=q1.y; dts[6]=q1.z; dts[7]=q1.w;
      dts[8]=q2.x; dts[9]=q2.y; dts[10]=q2.z; dts[11]=q2.w;
    }
    float dt_s[12], dtu[12];
#pragma unroll
    for (int cc = 0; cc < 12; ++cc) {
      float pre = fmaf(dts[cc], dtw, dtb);
      float v = (pre > 20.f) ? pre : log1pf(expf(pre));       // softplus
      dt_s[cc] = v;
      dtu[cc] = v * uvv[cc];
    }

    float y[12];
#pragma unroll
    for (int cc = 0; cc < 12; ++cc) y[cc] = 0.f;

#pragma unroll
    for (int n = 0; n < Nn; ++n) {
      const float4* Br = (const float4*)&xdl[xb + s * XSS + (1 + n) * 12];
      const float4* Cr = (const float4*)&xdl[xb + (1 - s) * XSS + (13 + n) * 12];
      float4 b0 = Br[0], b1 = Br[1], b2 = Br[2];
      float4 c0 = Cr[0], c1 = Cr[1], c2 = Cr[2];
      float Bv[12], Cv[12];
      Bv[0]=b0.x; Bv[1]=b0.y; Bv[2]=b0.z; Bv[3]=b0.w;
      Bv[4]=b1.x; Bv[5]=b1.y; Bv[6]=b1.z; Bv[7]=b1.w;
      Bv[8]=b2.x; Bv[9]=b2.y; Bv[10]=b2.z; Bv[11]=b2.w;
      Cv[0]=c0.x; Cv[1]=c0.y; Cv[2]=c0.z; Cv[3]=c0.w;
      Cv[4]=c1.x; Cv[5]=c1.y; Cv[6]=c1.z; Cv[7]=c1.w;
      Cv[8]=c2.x; Cv[9]=c2.y; Cv[10]=c2.z; Cv[11]=c2.w;
      float h = 0.f;
      float An = Ar[n];
#pragma unroll
      for (int cc = 0; cc < 12; ++cc) {
        float dA = expf(dt_s[cc] * An);
        h = fmaf(dA, h, dtu[cc] * Bv[cc]);
        y[cc] = fmaf(h, Cv[cc], y[cc]);
      }
    }

#pragma unroll
    for (int cc = 0; cc < 12; ++cc) y[cc] = fmaf(uvv[cc], Dv, y[cc]);

    float mu = 0.f;
#pragma unroll
    for (int cc = 0; cc < 12; ++cc) mu += y[cc];
    mu *= (1.f / CCn);
    float var = 0.f;
#pragma unroll
    for (int cc = 0; cc < 12; ++cc) { float t = y[cc] - mu; var = fmaf(t, t, var); }
    var *= (1.f / CCn);
    float rs = rsqrtf(var + 1e-5f);
    const float* ow = s ? on2w : on1w;
    const float* ob = s ? on2b : on1b;
#pragma unroll
    for (int cc = 0; cc < 12; ++cc)
      uS[ub + cc] = fmaf((y[cc] - mu) * rs, ow[cc], ob[cc]);
  }
  __syncthreads();

#pragma unroll
  for (int i = 0; i < 2; ++i) {
    int id = i * 512 + tid;
    if (id < 768) {
      int px4 = id & 3, ch = (id >> 2) % Cn, ss = id / 384;
      int g = ch >> 2, co = ch & 3;
      const float* ow2 = (ss ? opw1 : opw0) + g * 32 + co * 8;
      float a0 = 0.f, a1 = 0.f, a2 = 0.f, a3 = 0.f;
#pragma unroll
      for (int ci = 0; ci < 8; ++ci) {
        int e = g * 8 + ci;
        int dd = e / 12, cc = e % 12;
        int base = ss * USS + dd * UDS + cc;
        float w = ow2[ci];
        a0 = fmaf(uS[(px4 * 4 + 0) * UPXS + base], w, a0);
        a1 = fmaf(uS[(px4 * 4 + 1) * UPXS + base], w, a1);
        a2 = fmaf(uS[(px4 * 4 + 2) * UPXS + base], w, a2);
        a3 = fmaf(uS[(px4 * 4 + 3) * UPXS + base], w, a3);
      }
      size_t go = (((size_t)ss * Bn + b) * Cn + ch) * HWn + l0 + px4 * 4;
      float4 xrv = *(const float4*)&xr_ws[go];
      *(float4*)&z_ws[go] =
          make_float4(a0 + xrv.x, a1 + xrv.y, a2 + xrv.z, a3 + xrv.w);
    }
  }
}

// ---------------------------------------------------------------------------
// K4: weight transposes for the fused MLP. (unchanged)
// ---------------------------------------------------------------------------
__global__ void k_transpose_w(
    const float* __restrict__ w1r, const float* __restrict__ w1e,
    const float* __restrict__ w2r, const float* __restrict__ w2e,
    float* __restrict__ w1t, float* __restrict__ w2t)
{
  int idx = blockIdx.x * 256 + threadIdx.x;     // 0 .. 147455
  int which = idx / 36864;                      // 0:w1r 1:w1e 2:w2r 3:w2e
  int r = idx % 36864;
  if (which < 2) {
    int c = r / HDn, o = r % HDn;               // dest [c][o]
    const float* src = which ? w1e : w1r;       // src [o][c]
    w1t[which * 36864 + r] = src[o * Cn + c];
  } else {
    int o = r / Cn, c = r % Cn;                 // dest [o][c]
    const float* src = (which == 3) ? w2e : w2r; // src [c][o]
    w2t[(which - 2) * 36864 + r] = src[c * HDn + o];
  }
}

// ---------------------------------------------------------------------------
// K5 v2: fused MLP, hidden split in two 192-halves.
//  LDS 40.7 KB -> 4 blocks/CU (16 waves). fc2 uses b64 reads (2px x 6ch).
//  hS row stride 34: 8B-aligned float2, conflict-free fc2 reads.
// ---------------------------------------------------------------------------
#define HSS 34

__global__ __launch_bounds__(256, 4) void k_mlp(
    const float* __restrict__ z_all,
    const float* __restrict__ n1w, const float* __restrict__ n1b,
    const float* __restrict__ n2w, const float* __restrict__ n2b,
    const float* __restrict__ w1t_all, const float* __restrict__ b1r,
    const float* __restrict__ b1e,
    const float* __restrict__ w2t_all, const float* __restrict__ b2r,
    const float* __restrict__ b2e,
    float* __restrict__ out_all)
{
  __shared__ float zn[Cn * 32];        // 12288 B
  __shared__ float hS[192 * HSS];      // 26112 B
  __shared__ float red[2 * 8 * 32];    // 2048 B
  __shared__ float mus[32], rss[32];

  const int s    = blockIdx.y;
  const int tile = blockIdx.x;                 // 0..1023
  const int b    = (tile * 32) >> 14;
  const int l0   = (tile * 32) & (HWn - 1);
  const int tid  = threadIdx.x;

  const float* z   = z_all + ((size_t)s * Bn + b) * Cn * HWn + l0;
  float*       out = (float*)out_all + ((size_t)s * Bn + b) * Cn * HWn + l0;
  const float* nw  = s ? n2w : n1w;
  const float* nb  = s ? n2b : n1b;
  const float* w1t = w1t_all + s * 36864;
  const float* b1  = s ? b1e : b1r;
  const float* w2t = w2t_all + s * 36864;
  const float* b2  = s ? b2e : b2r;

  // ---- phase 0: load z tile + LN ----
  {
    const int px = tid & 31, part = tid >> 5;   // 8 parts x 12 channels
    float psum = 0.f, pss = 0.f;
#pragma unroll
    for (int i = 0; i < 12; ++i) {
      int c = part + 8 * i;
      float v = z[(size_t)c * HWn + px];
      zn[c * 32 + px] = v; psum += v; pss += v * v;
    }
    red[part * 32 + px] = psum;
    red[256 + part * 32 + px] = pss;
    __syncthreads();
    if (tid < 32) {
      float sm = 0.f, sq = 0.f;
#pragma unroll
      for (int p = 0; p < 8; ++p) { sm += red[p * 32 + tid]; sq += red[256 + p * 32 + tid]; }
      float mu = sm * (1.f / Cn);
      float var = sq * (1.f / Cn) - mu * mu;
      mus[tid] = mu; rss[tid] = rsqrtf(var + 1e-6f);
    }
    __syncthreads();
    float mu = mus[px], rs = rss[px];
#pragma unroll
    for (int i = 0; i < 12; ++i) {
      int c = part + 8 * i;
      float v = zn[c * 32 + px];
      zn[c * 32 + px] = fmaf((v - mu) * rs, nw[c], nb[c]);
    }
    __syncthreads();
  }

  const int pg   = (tid & 7) << 2;             // fc1 pixel base (4 px)
  const int og   = (tid >> 3) * 6;             // fc1 output base within half
  const int p2px = (tid & 15) * 2;             // fc2 pixel base (2 px)
  const int cg   = (tid >> 4) * 6;             // fc2 channel base (6 ch)

  float a2[6][2];
#pragma unroll
  for (int k = 0; k < 6; ++k) { a2[k][0] = 0.f; a2[k][1] = 0.f; }

#pragma unroll
  for (int hf = 0; hf < 2; ++hf) {
    // ---- fc1: 6 outputs x 4 px for this half ----
    float acc[6][4];
#pragma unroll
    for (int j = 0; j < 6; ++j)
#pragma unroll
      for (int i = 0; i < 4; ++i) acc[j][i] = 0.f;

    const float* w1base = w1t + hf * 192 + og;
    for (int c = 0; c < Cn; ++c) {
      float4 xv = *(const float4*)&zn[c * 32 + pg];
      const float* wr = w1base + c * HDn;
      float2 wa = *(const float2*)&wr[0];
      float2 wb = *(const float2*)&wr[2];
      float2 wc = *(const float2*)&wr[4];
      float w[6] = {wa.x, wa.y, wb.x, wb.y, wc.x, wc.y};
#pragma unroll
      for (int j = 0; j < 6; ++j) {
        acc[j][0] = fmaf(xv.x, w[j], acc[j][0]);
        acc[j][1] = fmaf(xv.y, w[j], acc[j][1]);
        acc[j][2] = fmaf(xv.z, w[j], acc[j][2]);
        acc[j][3] = fmaf(xv.w, w[j], acc[j][3]);
      }
    }
    // GELU + write hS (float2 pairs, stride 34)
#pragma unroll
    for (int j = 0; j < 6; ++j) {
      float bo = b1[hf * 192 + og + j];
      float g0 = acc[j][0] + bo, g1 = acc[j][1] + bo;
      float g2 = acc[j][2] + bo, g3 = acc[j][3] + bo;
      g0 = 0.5f * g0 * (1.f + erff(g0 * 0.70710678118654752f));
      g1 = 0.5f * g1 * (1.f + erff(g1 * 0.70710678118654752f));
      g2 = 0.5f * g2 * (1.f + erff(g2 * 0.70710678118654752f));
      g3 = 0.5f * g3 * (1.f + erff(g3 * 0.70710678118654752f));
      float* hr = &hS[(og + j) * HSS + pg];
      *(float2*)&hr[0] = make_float2(g0, g1);
      *(float2*)&hr[2] = make_float2(g2, g3);
    }
    __syncthreads();

    // ---- fc2 partial: accumulate this half's 192 o ----
    const float* w2base = w2t + (hf * 192) * Cn + cg;
    for (int o = 0; o < 192; ++o) {
      float2 hv = *(const float2*)&hS[o * HSS + p2px];
      const float* wr = w2base + o * Cn;
      float2 wa = *(const float2*)&wr[0];
      float2 wb = *(const float2*)&wr[2];
      float2 wc = *(const float2*)&wr[4];
      a2[0][0] = fmaf(hv.x, wa.x, a2[0][0]); a2[0][1] = fmaf(hv.y, wa.x, a2[0][1]);
      a2[1][0] = fmaf(hv.x, wa.y, a2[1][0]); a2[1][1] = fmaf(hv.y, wa.y, a2[1][1]);
      a2[2][0] = fmaf(hv.x, wb.x, a2[2][0]); a2[2][1] = fmaf(hv.y, wb.x, a2[2][1]);
      a2[3][0] = fmaf(hv.x, wb.y, a2[3][0]); a2[3][1] = fmaf(hv.y, wb.y, a2[3][1]);
      a2[4][0] = fmaf(hv.x, wc.x, a2[4][0]); a2[4][1] = fmaf(hv.y, wc.x, a2[4][1]);
      a2[5][0] = fmaf(hv.x, wc.y, a2[5][0]); a2[5][1] = fmaf(hv.y, wc.y, a2[5][1]);
    }
    __syncthreads();   // hS free for next half
  }

  // ---- epilogue: bias + residual -> out (float2) ----
#pragma unroll
  for (int k = 0; k < 6; ++k) {
    int c = cg + k;
    float bk = b2[c];
    size_t off = (size_t)c * HWn + p2px;
    float2 zv = *(const float2*)&z[off];
    *(float2*)&out[off] = make_float2(a2[k][0] + bk + zv.x, a2[k][1] + bk + zv.y);
  }
}

// ---------------------------------------------------------------------------
extern "C" void kernel_launch(void* const* d_in, const int* in_sizes, int n_in,
                              void* d_out, int out_size, void* d_ws, size_t ws_size,
                              hipStream_t stream)
{
  const float* x_rgb = (const float*)d_in[0];
  const float* x_e   = (const float*)d_in[1];
  const float* in1_w = (const float*)d_in[2];
  const float* in1_b = (const float*)d_in[3];
  const float* in2_w = (const float*)d_in[4];
  const float* in2_b = (const float*)d_in[5];
  const float* ipw0  = (const float*)d_in[6];
  const float* ipw1  = (const float*)d_in[7];
  const float* cw0   = (const float*)d_in[8];
  const float* cb0   = (const float*)d_in[9];
  const float* cw1   = (const float*)d_in[10];
  const float* cb1   = (const float*)d_in[11];
  const float* xprojw  = (const float*)d_in[12];
  const float* dtprojw = (const float*)d_in[13];
  const float* dtprojb = (const float*)d_in[14];
  const float* A_logs  = (const float*)d_in[15];
  const float* Ds      = (const float*)d_in[16];
  const float* on1w  = (const float*)d_in[17];
  const float* on1b  = (const float*)d_in[18];
  const float* on2w  = (const float*)d_in[19];
  const float* on2b  = (const float*)d_in[20];
  const float* opw0  = (const float*)d_in[21];
  const float* opw1  = (const float*)d_in[22];
  const float* n1w   = (const float*)d_in[23];
  const float* n1b   = (const float*)d_in[24];
  const float* n2w   = (const float*)d_in[25];
  const float* n2b   = (const float*)d_in[26];
  const float* w1r   = (const float*)d_in[27];
  const float* b1r   = (const float*)d_in[28];
  const float* w2r   = (const float*)d_in[29];
  const float* b2r   = (const float*)d_in[30];
  const float* w1e   = (const float*)d_in[31];
  const float* b1e   = (const float*)d_in[32];
  const float* w2e   = (const float*)d_in[33];
  const float* b2e   = (const float*)d_in[34];

  float* ws  = (float*)d_ws;
  float* xr  = ws;                              // 2*B*C*HW  = 6291456 f
  float* vz  = ws + (size_t)6291456;            // 2*B*E*HW  = 12582912 f (v, later z)
  float* ut  = ws + (size_t)18874368;           // 2*B*E*HW  = 12582912 f (u; reused for w1t/w2t)
  float* w1t = ut;                              // 2*36864 f (after k_ssm consumed u)
  float* w2t = ut + 73728;                      // 2*36864 f

  dim3 b256(256);

  k_ln_inproj<<<dim3(512, 2), b256, 0, stream>>>(
      x_rgb, x_e, in1_w, in1_b, in2_w, in2_b, ipw0, ipw1, xr, vz);

  k_dwconv_silu<<<dim3(64, En, 4), b256, 0, stream>>>(
      vz, cw0, cb0, cw1, cb1, ut);

  k_ssm<<<dim3(2048), dim3(512), 0, stream>>>(
      ut, xr, vz, xprojw, dtprojw, dtprojb, A_logs, Ds,
      on1w, on1b, on2w, on2b, opw0, opw1);

  // u (in ut) is dead now; reuse its space for the transposed MLP weights.
  k_transpose_w<<<dim3(576), b256, 0, stream>>>(w1r, w1e, w2r, w2e, w1t, w2t);

  k_mlp<<<dim3(1024, 2), b256, 0, stream>>>(
      vz, n1w, n1b, n2w, n2b, w1t, b1r, b1e, w2t, b2r, b2e, (float*)d_out);
}

// Round 11
// 565.985 us; speedup vs baseline: 1.1825x; 1.1825x over previous
//
#include <hip/hip_runtime.h>
#include <math.h>

#define HWn 16384
#define Hn  128
#define Wn  128
#define Bn  2
#define Cn  96
#define En  192
#define Gn  24
#define HEADn 16
#define CCn 12
#define Nn  12
#define HDn 384

// ---------------------------------------------------------------------------
// K1 v2: channel LayerNorm (eps 1e-6) + grouped 1x1 in-projection.
// (unchanged from round 10 — measured win, ~15 us)
// ---------------------------------------------------------------------------
#define ZS 68

__global__ __launch_bounds__(256, 4) void k_ln_inproj(
    const float* __restrict__ x0, const float* __restrict__ x1,
    const float* __restrict__ lw0, const float* __restrict__ lb0,
    const float* __restrict__ lw1, const float* __restrict__ lb1,
    const float* __restrict__ pw0, const float* __restrict__ pw1,
    float* __restrict__ xr, float* __restrict__ v)
{
  __shared__ __align__(16) float zn[Cn * ZS];   // 26112 B
  __shared__ float red[2 * 16 * 64];            // 8192 B
  __shared__ float mus[64], rss[64];

  const int s    = blockIdx.y;
  const int tile = blockIdx.x;                  // 0..511
  const int b  = (tile * 64) >> 14;
  const int l0 = (tile * 64) & (HWn - 1);
  const int tid = threadIdx.x;

  const float* x  = s ? x1  : x0;
  const float* lw = s ? lw1 : lw0;
  const float* lb = s ? lb1 : lb0;
  const float* pw = s ? pw1 : pw0;

  const int px4 = (tid & 15) * 4;               // pixel base (float4)
  const int cg0 = tid >> 4;                     // channel start, step 16

  const float* xp = x + (size_t)b * Cn * HWn + l0;
  float ps0=0.f,ps1=0.f,ps2=0.f,ps3=0.f, pq0=0.f,pq1=0.f,pq2=0.f,pq3=0.f;
#pragma unroll
  for (int i = 0; i < 6; ++i) {
    int ch = cg0 + 16 * i;
    float4 t = *(const float4*)&xp[(size_t)ch * HWn + px4];
    *(float4*)&zn[ch * ZS + px4] = t;
    ps0 += t.x; pq0 += t.x * t.x;
    ps1 += t.y; pq1 += t.y * t.y;
    ps2 += t.z; pq2 += t.z * t.z;
    ps3 += t.w; pq3 += t.w * t.w;
  }
  red[cg0 * 64 + px4 + 0] = ps0; red[1024 + cg0 * 64 + px4 + 0] = pq0;
  red[cg0 * 64 + px4 + 1] = ps1; red[1024 + cg0 * 64 + px4 + 1] = pq1;
  red[cg0 * 64 + px4 + 2] = ps2; red[1024 + cg0 * 64 + px4 + 2] = pq2;
  red[cg0 * 64 + px4 + 3] = ps3; red[1024 + cg0 * 64 + px4 + 3] = pq3;
  __syncthreads();
  if (tid < 64) {
    float sm = 0.f, sq = 0.f;
#pragma unroll
    for (int g = 0; g < 16; ++g) { sm += red[g * 64 + tid]; sq += red[1024 + g * 64 + tid]; }
    float mu = sm * (1.f / Cn);
    float var = sq * (1.f / Cn) - mu * mu;
    mus[tid] = mu; rss[tid] = rsqrtf(var + 1e-6f);
  }
  __syncthreads();

  const float m0 = mus[px4+0], m1 = mus[px4+1], m2 = mus[px4+2], m3 = mus[px4+3];
  const float r0 = rss[px4+0], r1 = rss[px4+1], r2 = rss[px4+2], r3 = rss[px4+3];
  float* xrp = xr + ((size_t)s * Bn + b) * Cn * HWn + l0;
#pragma unroll
  for (int i = 0; i < 6; ++i) {
    int ch = cg0 + 16 * i;
    float4 t = *(const float4*)&zn[ch * ZS + px4];
    float wch = lw[ch], bch = lb[ch];
    t.x = fmaf((t.x - m0) * r0, wch, bch);
    t.y = fmaf((t.y - m1) * r1, wch, bch);
    t.z = fmaf((t.z - m2) * r2, wch, bch);
    t.w = fmaf((t.w - m3) * r3, wch, bch);
    *(float4*)&zn[ch * ZS + px4] = t;
    *(float4*)&xrp[(size_t)ch * HWn + px4] = t;
  }
  __syncthreads();

  const int og  = (tid >> 4) * 12;
  const int pxg = (tid & 15) * 4;
  float* vp = v + ((size_t)s * Bn + b) * En * HWn + l0;
#pragma unroll
  for (int jo = 0; jo < 12; ++jo) {
    int o = og + jo, g = o >> 3;
    float4 wv = *(const float4*)&pw[g * 32 + (o & 7) * 4];
    float4 z0 = *(const float4*)&zn[(g * 4 + 0) * ZS + pxg];
    float4 z1 = *(const float4*)&zn[(g * 4 + 1) * ZS + pxg];
    float4 z2 = *(const float4*)&zn[(g * 4 + 2) * ZS + pxg];
    float4 z3 = *(const float4*)&zn[(g * 4 + 3) * ZS + pxg];
    float4 a;
    a.x = fmaf(z0.x, wv.x, fmaf(z1.x, wv.y, fmaf(z2.x, wv.z, z3.x * wv.w)));
    a.y = fmaf(z0.y, wv.x, fmaf(z1.y, wv.y, fmaf(z2.y, wv.z, z3.y * wv.w)));
    a.z = fmaf(z0.z, wv.x, fmaf(z1.z, wv.y, fmaf(z2.z, wv.z, z3.z * wv.w)));
    a.w = fmaf(z0.w, wv.x, fmaf(z1.w, wv.y, fmaf(z2.w, wv.z, z3.w * wv.w)));
    *(float4*)&vp[(size_t)o * HWn + pxg] = a;
  }
}

// ---------------------------------------------------------------------------
// K2: depthwise 3x3 conv + bias + SiLU. grid (64, 192, 4)  (unchanged)
// ---------------------------------------------------------------------------
__global__ __launch_bounds__(256) void k_dwconv_silu(
    const float* __restrict__ v,
    const float* __restrict__ cw0, const float* __restrict__ cb0,
    const float* __restrict__ cw1, const float* __restrict__ cb1,
    float* __restrict__ u)
{
  const int z = blockIdx.z;                 // s*2+b
  const int e = blockIdx.y;
  const int p = blockIdx.x * 256 + threadIdx.x;
  const int h = p >> 7, w = p & 127;
  const int s = z >> 1;
  const float* cw  = (s ? cw1 : cw0) + e * 9;
  const float bias = (s ? cb1 : cb0)[e];
  const float* src = v + ((size_t)z * En + e) * HWn;

  float acc = bias;
#pragma unroll
  for (int kh = 0; kh < 3; ++kh) {
    int hh = h + kh - 1;
    if (hh < 0 || hh >= Hn) continue;
#pragma unroll
    for (int kw = 0; kw < 3; ++kw) {
      int ww = w + kw - 1;
      if (ww < 0 || ww >= Wn) continue;
      acc = fmaf(src[hh * Wn + ww], cw[kh * 3 + kw], acc);
    }
  }
  float sig = 1.f / (1.f + expf(-acc));
  u[((size_t)z * En + e) * HWn + p] = acc * sig;
}

// ---------------------------------------------------------------------------
// K3: SSM core, conflict-free LDS edition. (unchanged from round 6)
// ---------------------------------------------------------------------------
#define UPXS 417
#define USS  208
#define UDS  13
#define XPXS 604
#define XSS  300

__global__ __launch_bounds__(512) void k_ssm(
    const float* __restrict__ u_ws, const float* __restrict__ xr_ws,
    float* __restrict__ z_ws,
    const float* __restrict__ xprojw, const float* __restrict__ dtprojw,
    const float* __restrict__ dtprojb, const float* __restrict__ A_logs,
    const float* __restrict__ Ds,
    const float* __restrict__ on1w, const float* __restrict__ on1b,
    const float* __restrict__ on2w, const float* __restrict__ on2b,
    const float* __restrict__ opw0, const float* __restrict__ opw1)
{
  __shared__ __align__(16) float uS[16 * UPXS];    // 6672 f = 26688 B
  __shared__ __align__(16) float xdl[16 * XPXS];   // 9664 f = 38656 B

  const int tid  = threadIdx.x;
  const int tile = blockIdx.x;
  const int b  = (tile * 16) >> 14;
  const int l0 = (tile * 16) & (HWn - 1);

  const int p2px = tid >> 5, p2s = (tid >> 4) & 1, p2d = tid & 15;
  const float dtw = dtprojw[p2s * HEADn + p2d];
  const float dtb = dtprojb[p2s * HEADn + p2d];
  const float Dv  = Ds[p2s * HEADn + p2d];
  float Ar[Nn];
  {
    const float4* ap = (const float4*)&A_logs[(p2s * HEADn + p2d) * Nn];
    float4 a0 = ap[0], a1 = ap[1], a2 = ap[2];
    Ar[0]=-expf(a0.x); Ar[1]=-expf(a0.y); Ar[2]=-expf(a0.z); Ar[3]=-expf(a0.w);
    Ar[4]=-expf(a1.x); Ar[5]=-expf(a1.y); Ar[6]=-expf(a1.z); Ar[7]=-expf(a1.w);
    Ar[8]=-expf(a2.x); Ar[9]=-expf(a2.y); Ar[10]=-expf(a2.z); Ar[11]=-expf(a2.w);
  }

#pragma unroll
  for (int i = 0; i < 3; ++i) {
    int id = i * 512 + tid;
    int px4 = id & 3, rest = id >> 2;
    int ch = rest % En, s2 = rest / En;
    float4 t = *(const float4*)&u_ws[(((size_t)s2 * Bn + b) * En + ch) * HWn + l0 + px4 * 4];
    int dd = ch / 12, cc = ch % 12;
    int base = s2 * USS + dd * UDS + cc;
    uS[(px4 * 4 + 0) * UPXS + base] = t.x;
    uS[(px4 * 4 + 1) * UPXS + base] = t.y;
    uS[(px4 * 4 + 2) * UPXS + base] = t.z;
    uS[(px4 * 4 + 3) * UPXS + base] = t.w;
  }
  __syncthreads();

#pragma unroll
  for (int j = 0; j < 2; ++j) {
    int id = j * 512 + tid;
    if (id < 800) {
      int px = id & 15, sr = id >> 4;
      int s2 = sr / 25, r = sr % 25;
      const float4* xw4 = (const float4*)&xprojw[(s2 * 25 + r) * HEADn];
      float4 w0 = xw4[0], w1 = xw4[1], w2 = xw4[2], w3 = xw4[3];
      float wv[16];
      wv[0]=w0.x; wv[1]=w0.y; wv[2]=w0.z; wv[3]=w0.w;
      wv[4]=w1.x; wv[5]=w1.y; wv[6]=w1.z; wv[7]=w1.w;
      wv[8]=w2.x; wv[9]=w2.y; wv[10]=w2.z; wv[11]=w2.w;
      wv[12]=w3.x; wv[13]=w3.y; wv[14]=w3.z; wv[15]=w3.w;
      int ub = px * UPXS + s2 * USS;
      float acc[12];
#pragma unroll
      for (int cc = 0; cc < 12; ++cc) acc[cc] = 0.f;
#pragma unroll
      for (int dd = 0; dd < HEADn; ++dd) {
        float w = wv[dd];
        int ua = ub + dd * UDS;
#pragma unroll
        for (int cc = 0; cc < 12; ++cc)
          acc[cc] = fmaf(uS[ua + cc], w, acc[cc]);
      }
      float* xp = &xdl[px * XPXS + s2 * XSS + r * 12];
      *(float4*)&xp[0] = make_float4(acc[0], acc[1], acc[2], acc[3]);
      *(float4*)&xp[4] = make_float4(acc[4], acc[5], acc[6], acc[7]);
      *(float4*)&xp[8] = make_float4(acc[8], acc[9], acc[10], acc[11]);
    }
  }
  __syncthreads();

  {
    const int px = p2px, s = p2s, d = p2d;
    const int ub = px * UPXS + s * USS + d * UDS;
    float uvv[12];
#pragma unroll
    for (int cc = 0; cc < 12; ++cc) uvv[cc] = uS[ub + cc];

    const int xb = px * XPXS;
    float dts[12];
    {
      const float4* dr = (const float4*)&xdl[xb + s * XSS];   // r = 0
      float4 q0 = dr[0], q1 = dr[1], q2 = dr[2];
      dts[0]=q0.x; dts[1]=q0.y; dts[2]=q0.z; dts[3]=q0.w;
      dts[4]=q1.x; dts[5]=q1.y; dts[6]=q1.z; dts[7]=q1.w;
      dts[8]=q2.x; dts[9]=q2.y; dts[10]=q2.z; dts[11]=q2.w;
    }
    float dt_s[12], dtu[12];
#pragma unroll
    for (int cc = 0; cc < 12; ++cc) {
      float pre = fmaf(dts[cc], dtw, dtb);
      float v = (pre > 20.f) ? pre : log1pf(expf(pre));       // softplus
      dt_s[cc] = v;
      dtu[cc] = v * uvv[cc];
    }

    float y[12];
#pragma unroll
    for (int cc = 0; cc < 12; ++cc) y[cc] = 0.f;

#pragma unroll
    for (int n = 0; n < Nn; ++n) {
      const float4* Br = (const float4*)&xdl[xb + s * XSS + (1 + n) * 12];
      const float4* Cr = (const float4*)&xdl[xb + (1 - s) * XSS + (13 + n) * 12];
      float4 b0 = Br[0], b1 = Br[1], b2 = Br[2];
      float4 c0 = Cr[0], c1 = Cr[1], c2 = Cr[2];
      float Bv[12], Cv[12];
      Bv[0]=b0.x; Bv[1]=b0.y; Bv[2]=b0.z; Bv[3]=b0.w;
      Bv[4]=b1.x; Bv[5]=b1.y; Bv[6]=b1.z; Bv[7]=b1.w;
      Bv[8]=b2.x; Bv[9]=b2.y; Bv[10]=b2.z; Bv[11]=b2.w;
      Cv[0]=c0.x; Cv[1]=c0.y; Cv[2]=c0.z; Cv[3]=c0.w;
      Cv[4]=c1.x; Cv[5]=c1.y; Cv[6]=c1.z; Cv[7]=c1.w;
      Cv[8]=c2.x; Cv[9]=c2.y; Cv[10]=c2.z; Cv[11]=c2.w;
      float h = 0.f;
      float An = Ar[n];
#pragma unroll
      for (int cc = 0; cc < 12; ++cc) {
        float dA = expf(dt_s[cc] * An);
        h = fmaf(dA, h, dtu[cc] * Bv[cc]);
        y[cc] = fmaf(h, Cv[cc], y[cc]);
      }
    }

#pragma unroll
    for (int cc = 0; cc < 12; ++cc) y[cc] = fmaf(uvv[cc], Dv, y[cc]);

    float mu = 0.f;
#pragma unroll
    for (int cc = 0; cc < 12; ++cc) mu += y[cc];
    mu *= (1.f / CCn);
    float var = 0.f;
#pragma unroll
    for (int cc = 0; cc < 12; ++cc) { float t = y[cc] - mu; var = fmaf(t, t, var); }
    var *= (1.f / CCn);
    float rs = rsqrtf(var + 1e-5f);
    const float* ow = s ? on2w : on1w;
    const float* ob = s ? on2b : on1b;
#pragma unroll
    for (int cc = 0; cc < 12; ++cc)
      uS[ub + cc] = fmaf((y[cc] - mu) * rs, ow[cc], ob[cc]);
  }
  __syncthreads();

#pragma unroll
  for (int i = 0; i < 2; ++i) {
    int id = i * 512 + tid;
    if (id < 768) {
      int px4 = id & 3, ch = (id >> 2) % Cn, ss = id / 384;
      int g = ch >> 2, co = ch & 3;
      const float* ow2 = (ss ? opw1 : opw0) + g * 32 + co * 8;
      float a0 = 0.f, a1 = 0.f, a2 = 0.f, a3 = 0.f;
#pragma unroll
      for (int ci = 0; ci < 8; ++ci) {
        int e = g * 8 + ci;
        int dd = e / 12, cc = e % 12;
        int base = ss * USS + dd * UDS + cc;
        float w = ow2[ci];
        a0 = fmaf(uS[(px4 * 4 + 0) * UPXS + base], w, a0);
        a1 = fmaf(uS[(px4 * 4 + 1) * UPXS + base], w, a1);
        a2 = fmaf(uS[(px4 * 4 + 2) * UPXS + base], w, a2);
        a3 = fmaf(uS[(px4 * 4 + 3) * UPXS + base], w, a3);
      }
      size_t go = (((size_t)ss * Bn + b) * Cn + ch) * HWn + l0 + px4 * 4;
      float4 xrv = *(const float4*)&xr_ws[go];
      *(float4*)&z_ws[go] =
          make_float4(a0 + xrv.x, a1 + xrv.y, a2 + xrv.z, a3 + xrv.w);
    }
  }
}

// ---------------------------------------------------------------------------
// K4 v2: transpose only w1 -> w1t[s][c][o].  (w2 used in original layout now)
// ---------------------------------------------------------------------------
__global__ void k_transpose_w1(
    const float* __restrict__ w1r, const float* __restrict__ w1e,
    float* __restrict__ w1t)
{
  int idx = blockIdx.x * 256 + threadIdx.x;     // 0 .. 73727
  if (idx < 2 * 36864) {
    int which = idx / 36864;
    int r = idx % 36864;
    int c = r / HDn, o = r % HDn;               // dest [c][o]
    const float* src = which ? w1e : w1r;       // src [o][c]
    w1t[idx] = src[o * Cn + c];
  }
}

// ---------------------------------------------------------------------------
// K5 v3: fused MLP — v1 structure (single pass, 64KB LDS, 2 blocks/CU),
// with vectorized weight loads:
//  fc1: 12 out x 4 px, w1t row chunk = 3x float4, unroll 2.
//  fc2: 3 ch x 4 px, ORIGINAL w2[c][o] layout -> 4 consecutive o = 1 float4;
//       per 4-o step: 4 LDS b128 + 3 VMEM dwordx4 + 48 FMA (vs 28 loads in v1).
// Summation order (c ascending, o ascending) identical to v1.
// ---------------------------------------------------------------------------
__global__ __launch_bounds__(256, 2) void k_mlp(
    const float* __restrict__ z_all,
    const float* __restrict__ n1w, const float* __restrict__ n1b,
    const float* __restrict__ n2w, const float* __restrict__ n2b,
    const float* __restrict__ w1t_all, const float* __restrict__ b1r,
    const float* __restrict__ b1e,
    const float* __restrict__ w2r_, const float* __restrict__ w2e_,
    const float* __restrict__ b2r, const float* __restrict__ b2e,
    float* __restrict__ out_all)
{
  __shared__ __align__(16) float zn[Cn * 32];   // 12 KB
  __shared__ __align__(16) float hS[HDn * 32];  // 48 KB
  __shared__ float red[2 * 8 * 32];             // 2 KB
  __shared__ float mus[32], rss[32];

  const int s    = blockIdx.y;
  const int tile = blockIdx.x;                 // 0..1023
  const int b    = (tile * 32) >> 14;
  const int l0   = (tile * 32) & (HWn - 1);
  const int tid  = threadIdx.x;

  const float* z   = z_all + ((size_t)s * Bn + b) * Cn * HWn + l0;
  float*       out = (float*)out_all + ((size_t)s * Bn + b) * Cn * HWn + l0;
  const float* nw  = s ? n2w : n1w;
  const float* nb  = s ? n2b : n1b;
  const float* w1t = w1t_all + s * 36864;
  const float* b1  = s ? b1e : b1r;
  const float* w2  = s ? w2e_ : w2r_;          // [96][384] original layout
  const float* b2  = s ? b2e : b2r;

  // ---- phase 0: load z tile + LN ----
  {
    const int px = tid & 31, part = tid >> 5;   // 8 parts x 12 channels
    float psum = 0.f, pss = 0.f;
#pragma unroll
    for (int i = 0; i < 12; ++i) {
      int c = part + 8 * i;
      float v = z[(size_t)c * HWn + px];
      zn[c * 32 + px] = v; psum += v; pss += v * v;
    }
    red[part * 32 + px] = psum;
    red[256 + part * 32 + px] = pss;
    __syncthreads();
    if (tid < 32) {
      float sm = 0.f, sq = 0.f;
#pragma unroll
      for (int p = 0; p < 8; ++p) { sm += red[p * 32 + tid]; sq += red[256 + p * 32 + tid]; }
      float mu = sm * (1.f / Cn);
      float var = sq * (1.f / Cn) - mu * mu;
      mus[tid] = mu; rss[tid] = rsqrtf(var + 1e-6f);
    }
    __syncthreads();
    float mu = mus[px], rs = rss[px];
#pragma unroll
    for (int i = 0; i < 12; ++i) {
      int c = part + 8 * i;
      float v = zn[c * 32 + px];
      zn[c * 32 + px] = fmaf((v - mu) * rs, nw[c], nb[c]);
    }
    __syncthreads();
  }

  const int pg = (tid & 7) << 2;               // pixel base 0,4,...,28

  // ---- phase 1: fc1 + GELU -> hS (12 out x 4 px, float4 weight loads) ----
  {
    const int og = (tid >> 3) * 12;            // output base 0..372 (48B-aligned)
    float acc[12][4];
#pragma unroll
    for (int j = 0; j < 12; ++j)
#pragma unroll
      for (int i = 0; i < 4; ++i) acc[j][i] = 0.f;

#pragma unroll 2
    for (int c = 0; c < Cn; ++c) {
      float4 xv = *(const float4*)&zn[c * 32 + pg];
      const float4* wr = (const float4*)&w1t[c * HDn + og];
      float4 wq0 = wr[0], wq1 = wr[1], wq2 = wr[2];
      float w[12] = {wq0.x, wq0.y, wq0.z, wq0.w,
                     wq1.x, wq1.y, wq1.z, wq1.w,
                     wq2.x, wq2.y, wq2.z, wq2.w};
#pragma unroll
      for (int j = 0; j < 12; ++j) {
        acc[j][0] = fmaf(xv.x, w[j], acc[j][0]);
        acc[j][1] = fmaf(xv.y, w[j], acc[j][1]);
        acc[j][2] = fmaf(xv.z, w[j], acc[j][2]);
        acc[j][3] = fmaf(xv.w, w[j], acc[j][3]);
      }
    }
#pragma unroll
    for (int j = 0; j < 12; ++j) {
      float bo = b1[og + j];
      float g0 = acc[j][0] + bo, g1 = acc[j][1] + bo;
      float g2 = acc[j][2] + bo, g3 = acc[j][3] + bo;
      g0 = 0.5f * g0 * (1.f + erff(g0 * 0.70710678118654752f));
      g1 = 0.5f * g1 * (1.f + erff(g1 * 0.70710678118654752f));
      g2 = 0.5f * g2 * (1.f + erff(g2 * 0.70710678118654752f));
      g3 = 0.5f * g3 * (1.f + erff(g3 * 0.70710678118654752f));
      *(float4*)&hS[(og + j) * 32 + pg] = make_float4(g0, g1, g2, g3);
    }
  }
  __syncthreads();

  // ---- phase 2: fc2 + bias + residual -> out (3 ch x 4 px, 4-o steps) ----
  {
    const int cg = (tid >> 3) * 3;             // out-channel base 0..93
    float a0[4], a1[4], a2[4];
#pragma unroll
    for (int i = 0; i < 4; ++i) { a0[i] = 0.f; a1[i] = 0.f; a2[i] = 0.f; }

    const float* w2s0 = w2 + (size_t)(cg + 0) * HDn;
    const float* w2s1 = w2 + (size_t)(cg + 1) * HDn;
    const float* w2s2 = w2 + (size_t)(cg + 2) * HDn;

    for (int o4 = 0; o4 < HDn; o4 += 4) {
      float4 h0 = *(const float4*)&hS[(o4 + 0) * 32 + pg];
      float4 h1 = *(const float4*)&hS[(o4 + 1) * 32 + pg];
      float4 h2 = *(const float4*)&hS[(o4 + 2) * 32 + pg];
      float4 h3 = *(const float4*)&hS[(o4 + 3) * 32 + pg];
      float4 wA = *(const float4*)&w2s0[o4];
      float4 wB = *(const float4*)&w2s1[o4];
      float4 wC = *(const float4*)&w2s2[o4];
      // o ascending within each accumulator (same order as v1)
      a0[0] = fmaf(h3.x, wA.w, fmaf(h2.x, wA.z, fmaf(h1.x, wA.y, fmaf(h0.x, wA.x, a0[0]))));
      a0[1] = fmaf(h3.y, wA.w, fmaf(h2.y, wA.z, fmaf(h1.y, wA.y, fmaf(h0.y, wA.x, a0[1]))));
      a0[2] = fmaf(h3.z, wA.w, fmaf(h2.z, wA.z, fmaf(h1.z, wA.y, fmaf(h0.z, wA.x, a0[2]))));
      a0[3] = fmaf(h3.w, wA.w, fmaf(h2.w, wA.z, fmaf(h1.w, wA.y, fmaf(h0.w, wA.x, a0[3]))));
      a1[0] = fmaf(h3.x, wB.w, fmaf(h2.x, wB.z, fmaf(h1.x, wB.y, fmaf(h0.x, wB.x, a1[0]))));
      a1[1] = fmaf(h3.y, wB.w, fmaf(h2.y, wB.z, fmaf(h1.y, wB.y, fmaf(h0.y, wB.x, a1[1]))));
      a1[2] = fmaf(h3.z, wB.w, fmaf(h2.z, wB.z, fmaf(h1.z, wB.y, fmaf(h0.z, wB.x, a1[2]))));
      a1[3] = fmaf(h3.w, wB.w, fmaf(h2.w, wB.z, fmaf(h1.w, wB.y, fmaf(h0.w, wB.x, a1[3]))));
      a2[0] = fmaf(h3.x, wC.w, fmaf(h2.x, wC.z, fmaf(h1.x, wC.y, fmaf(h0.x, wC.x, a2[0]))));
      a2[1] = fmaf(h3.y, wC.w, fmaf(h2.y, wC.z, fmaf(h1.y, wC.y, fmaf(h0.y, wC.x, a2[1]))));
      a2[2] = fmaf(h3.z, wC.w, fmaf(h2.z, wC.z, fmaf(h1.z, wC.y, fmaf(h0.z, wC.x, a2[2]))));
      a2[3] = fmaf(h3.w, wC.w, fmaf(h2.w, wC.z, fmaf(h1.w, wC.y, fmaf(h0.w, wC.x, a2[3]))));
    }
#pragma unroll
    for (int k = 0; k < 3; ++k) {
      int c = cg + k;
      float bk = b2[c];
      const float* ak = (k == 0) ? a0 : (k == 1) ? a1 : a2;
#pragma unroll
      for (int i = 0; i < 4; ++i) {
        size_t off = (size_t)c * HWn + pg + i;
        out[off] = ak[i] + bk + z[off];
      }
    }
  }
}

// ---------------------------------------------------------------------------
extern "C" void kernel_launch(void* const* d_in, const int* in_sizes, int n_in,
                              void* d_out, int out_size, void* d_ws, size_t ws_size,
                              hipStream_t stream)
{
  const float* x_rgb = (const float*)d_in[0];
  const float* x_e   = (const float*)d_in[1];
  const float* in1_w = (const float*)d_in[2];
  const float* in1_b = (const float*)d_in[3];
  const float* in2_w = (const float*)d_in[4];
  const float* in2_b = (const float*)d_in[5];
  const float* ipw0  = (const float*)d_in[6];
  const float* ipw1  = (const float*)d_in[7];
  const float* cw0   = (const float*)d_in[8];
  const float* cb0   = (const float*)d_in[9];
  const float* cw1   = (const float*)d_in[10];
  const float* cb1   = (const float*)d_in[11];
  const float* xprojw  = (const float*)d_in[12];
  const float* dtprojw = (const float*)d_in[13];
  const float* dtprojb = (const float*)d_in[14];
  const float* A_logs  = (const float*)d_in[15];
  const float* Ds      = (const float*)d_in[16];
  const float* on1w  = (const float*)d_in[17];
  const float* on1b  = (const float*)d_in[18];
  const float* on2w  = (const float*)d_in[19];
  const float* on2b  = (const float*)d_in[20];
  const float* opw0  = (const float*)d_in[21];
  const float* opw1  = (const float*)d_in[22];
  const float* n1w   = (const float*)d_in[23];
  const float* n1b   = (const float*)d_in[24];
  const float* n2w   = (const float*)d_in[25];
  const float* n2b   = (const float*)d_in[26];
  const float* w1r   = (const float*)d_in[27];
  const float* b1r   = (const float*)d_in[28];
  const float* w2r   = (const float*)d_in[29];
  const float* b2r   = (const float*)d_in[30];
  const float* w1e   = (const float*)d_in[31];
  const float* b1e   = (const float*)d_in[32];
  const float* w2e   = (const float*)d_in[33];
  const float* b2e   = (const float*)d_in[34];

  float* ws  = (float*)d_ws;
  float* xr  = ws;                              // 2*B*C*HW  = 6291456 f
  float* vz  = ws + (size_t)6291456;            // 2*B*E*HW  = 12582912 f (v, later z)
  float* ut  = ws + (size_t)18874368;           // 2*B*E*HW  = 12582912 f (u; reused for w1t)
  float* w1t = ut;                              // 2*36864 f (after k_ssm consumed u)

  dim3 b256(256);

  k_ln_inproj<<<dim3(512, 2), b256, 0, stream>>>(
      x_rgb, x_e, in1_w, in1_b, in2_w, in2_b, ipw0, ipw1, xr, vz);

  k_dwconv_silu<<<dim3(64, En, 4), b256, 0, stream>>>(
      vz, cw0, cb0, cw1, cb1, ut);

  k_ssm<<<dim3(2048), dim3(512), 0, stream>>>(
      ut, xr, vz, xprojw, dtprojw, dtprojb, A_logs, Ds,
      on1w, on1b, on2w, on2b, opw0, opw1);

  // u (in ut) is dead now; reuse its space for the transposed w1.
  k_transpose_w1<<<dim3(288), b256, 0, stream>>>(w1r, w1e, w1t);

  k_mlp<<<dim3(1024, 2), b256, 0, stream>>>(
      vz, n1w, n1b, n2w, n2b, w1t, b1r, b1e, w2r, w2e, b2r, b2e, (float*)d_out);
}

// Round 12
// 552.271 us; speedup vs baseline: 1.2118x; 1.0248x over previous
//
#include <hip/hip_runtime.h>
#include <math.h>

#define HWn 16384
#define Hn  128
#define Wn  128
#define Bn  2
#define Cn  96
#define En  192
#define Gn  24
#define HEADn 16
#define CCn 12
#define Nn  12
#define HDn 384

// ---------------------------------------------------------------------------
// K1 v2: channel LayerNorm (eps 1e-6) + grouped 1x1 in-projection. (frozen)
// ---------------------------------------------------------------------------
#define ZS 68

__global__ __launch_bounds__(256, 4) void k_ln_inproj(
    const float* __restrict__ x0, const float* __restrict__ x1,
    const float* __restrict__ lw0, const float* __restrict__ lb0,
    const float* __restrict__ lw1, const float* __restrict__ lb1,
    const float* __restrict__ pw0, const float* __restrict__ pw1,
    float* __restrict__ xr, float* __restrict__ v)
{
  __shared__ __align__(16) float zn[Cn * ZS];   // 26112 B
  __shared__ float red[2 * 16 * 64];            // 8192 B
  __shared__ float mus[64], rss[64];

  const int s    = blockIdx.y;
  const int tile = blockIdx.x;                  // 0..511
  const int b  = (tile * 64) >> 14;
  const int l0 = (tile * 64) & (HWn - 1);
  const int tid = threadIdx.x;

  const float* x  = s ? x1  : x0;
  const float* lw = s ? lw1 : lw0;
  const float* lb = s ? lb1 : lb0;
  const float* pw = s ? pw1 : pw0;

  const int px4 = (tid & 15) * 4;               // pixel base (float4)
  const int cg0 = tid >> 4;                     // channel start, step 16

  const float* xp = x + (size_t)b * Cn * HWn + l0;
  float ps0=0.f,ps1=0.f,ps2=0.f,ps3=0.f, pq0=0.f,pq1=0.f,pq2=0.f,pq3=0.f;
#pragma unroll
  for (int i = 0; i < 6; ++i) {
    int ch = cg0 + 16 * i;
    float4 t = *(const float4*)&xp[(size_t)ch * HWn + px4];
    *(float4*)&zn[ch * ZS + px4] = t;
    ps0 += t.x; pq0 += t.x * t.x;
    ps1 += t.y; pq1 += t.y * t.y;
    ps2 += t.z; pq2 += t.z * t.z;
    ps3 += t.w; pq3 += t.w * t.w;
  }
  red[cg0 * 64 + px4 + 0] = ps0; red[1024 + cg0 * 64 + px4 + 0] = pq0;
  red[cg0 * 64 + px4 + 1] = ps1; red[1024 + cg0 * 64 + px4 + 1] = pq1;
  red[cg0 * 64 + px4 + 2] = ps2; red[1024 + cg0 * 64 + px4 + 2] = pq2;
  red[cg0 * 64 + px4 + 3] = ps3; red[1024 + cg0 * 64 + px4 + 3] = pq3;
  __syncthreads();
  if (tid < 64) {
    float sm = 0.f, sq = 0.f;
#pragma unroll
    for (int g = 0; g < 16; ++g) { sm += red[g * 64 + tid]; sq += red[1024 + g * 64 + tid]; }
    float mu = sm * (1.f / Cn);
    float var = sq * (1.f / Cn) - mu * mu;
    mus[tid] = mu; rss[tid] = rsqrtf(var + 1e-6f);
  }
  __syncthreads();

  const float m0 = mus[px4+0], m1 = mus[px4+1], m2 = mus[px4+2], m3 = mus[px4+3];
  const float r0 = rss[px4+0], r1 = rss[px4+1], r2 = rss[px4+2], r3 = rss[px4+3];
  float* xrp = xr + ((size_t)s * Bn + b) * Cn * HWn + l0;
#pragma unroll
  for (int i = 0; i < 6; ++i) {
    int ch = cg0 + 16 * i;
    float4 t = *(const float4*)&zn[ch * ZS + px4];
    float wch = lw[ch], bch = lb[ch];
    t.x = fmaf((t.x - m0) * r0, wch, bch);
    t.y = fmaf((t.y - m1) * r1, wch, bch);
    t.z = fmaf((t.z - m2) * r2, wch, bch);
    t.w = fmaf((t.w - m3) * r3, wch, bch);
    *(float4*)&zn[ch * ZS + px4] = t;
    *(float4*)&xrp[(size_t)ch * HWn + px4] = t;
  }
  __syncthreads();

  const int og  = (tid >> 4) * 12;
  const int pxg = (tid & 15) * 4;
  float* vp = v + ((size_t)s * Bn + b) * En * HWn + l0;
#pragma unroll
  for (int jo = 0; jo < 12; ++jo) {
    int o = og + jo, g = o >> 3;
    float4 wv = *(const float4*)&pw[g * 32 + (o & 7) * 4];
    float4 z0 = *(const float4*)&zn[(g * 4 + 0) * ZS + pxg];
    float4 z1 = *(const float4*)&zn[(g * 4 + 1) * ZS + pxg];
    float4 z2 = *(const float4*)&zn[(g * 4 + 2) * ZS + pxg];
    float4 z3 = *(const float4*)&zn[(g * 4 + 3) * ZS + pxg];
    float4 a;
    a.x = fmaf(z0.x, wv.x, fmaf(z1.x, wv.y, fmaf(z2.x, wv.z, z3.x * wv.w)));
    a.y = fmaf(z0.y, wv.x, fmaf(z1.y, wv.y, fmaf(z2.y, wv.z, z3.y * wv.w)));
    a.z = fmaf(z0.z, wv.x, fmaf(z1.z, wv.y, fmaf(z2.z, wv.z, z3.z * wv.w)));
    a.w = fmaf(z0.w, wv.x, fmaf(z1.w, wv.y, fmaf(z2.w, wv.z, z3.w * wv.w)));
    *(float4*)&vp[(size_t)o * HWn + pxg] = a;
  }
}

// ---------------------------------------------------------------------------
// K2: depthwise 3x3 conv + bias + SiLU. grid (64, 192, 4)  (frozen)
// ---------------------------------------------------------------------------
__global__ __launch_bounds__(256) void k_dwconv_silu(
    const float* __restrict__ v,
    const float* __restrict__ cw0, const float* __restrict__ cb0,
    const float* __restrict__ cw1, const float* __restrict__ cb1,
    float* __restrict__ u)
{
  const int z = blockIdx.z;                 // s*2+b
  const int e = blockIdx.y;
  const int p = blockIdx.x * 256 + threadIdx.x;
  const int h = p >> 7, w = p & 127;
  const int s = z >> 1;
  const float* cw  = (s ? cw1 : cw0) + e * 9;
  const float bias = (s ? cb1 : cb0)[e];
  const float* src = v + ((size_t)z * En + e) * HWn;

  float acc = bias;
#pragma unroll
  for (int kh = 0; kh < 3; ++kh) {
    int hh = h + kh - 1;
    if (hh < 0 || hh >= Hn) continue;
#pragma unroll
    for (int kw = 0; kw < 3; ++kw) {
      int ww = w + kw - 1;
      if (ww < 0 || ww >= Wn) continue;
      acc = fmaf(src[hh * Wn + ww], cw[kh * 3 + kw], acc);
    }
  }
  float sig = 1.f / (1.f + expf(-acc));
  u[((size_t)z * En + e) * HWn + p] = acc * sig;
}

// ---------------------------------------------------------------------------
// K3: SSM core, conflict-free LDS edition. (frozen)
// ---------------------------------------------------------------------------
#define UPXS 417
#define USS  208
#define UDS  13
#define XPXS 604
#define XSS  300

__global__ __launch_bounds__(512) void k_ssm(
    const float* __restrict__ u_ws, const float* __restrict__ xr_ws,
    float* __restrict__ z_ws,
    const float* __restrict__ xprojw, const float* __restrict__ dtprojw,
    const float* __restrict__ dtprojb, const float* __restrict__ A_logs,
    const float* __restrict__ Ds,
    const float* __restrict__ on1w, const float* __restrict__ on1b,
    const float* __restrict__ on2w, const float* __restrict__ on2b,
    const float* __restrict__ opw0, const float* __restrict__ opw1)
{
  __shared__ __align__(16) float uS[16 * UPXS];    // 6672 f = 26688 B
  __shared__ __align__(16) float xdl[16 * XPXS];   // 9664 f = 38656 B

  const int tid  = threadIdx.x;
  const int tile = blockIdx.x;
  const int b  = (tile * 16) >> 14;
  const int l0 = (tile * 16) & (HWn - 1);

  const int p2px = tid >> 5, p2s = (tid >> 4) & 1, p2d = tid & 15;
  const float dtw = dtprojw[p2s * HEADn + p2d];
  const float dtb = dtprojb[p2s * HEADn + p2d];
  const float Dv  = Ds[p2s * HEADn + p2d];
  float Ar[Nn];
  {
    const float4* ap = (const float4*)&A_logs[(p2s * HEADn + p2d) * Nn];
    float4 a0 = ap[0], a1 = ap[1], a2 = ap[2];
    Ar[0]=-expf(a0.x); Ar[1]=-expf(a0.y); Ar[2]=-expf(a0.z); Ar[3]=-expf(a0.w);
    Ar[4]=-expf(a1.x); Ar[5]=-expf(a1.y); Ar[6]=-expf(a1.z); Ar[7]=-expf(a1.w);
    Ar[8]=-expf(a2.x); Ar[9]=-expf(a2.y); Ar[10]=-expf(a2.z); Ar[11]=-expf(a2.w);
  }

#pragma unroll
  for (int i = 0; i < 3; ++i) {
    int id = i * 512 + tid;
    int px4 = id & 3, rest = id >> 2;
    int ch = rest % En, s2 = rest / En;
    float4 t = *(const float4*)&u_ws[(((size_t)s2 * Bn + b) * En + ch) * HWn + l0 + px4 * 4];
    int dd = ch / 12, cc = ch % 12;
    int base = s2 * USS + dd * UDS + cc;
    uS[(px4 * 4 + 0) * UPXS + base] = t.x;
    uS[(px4 * 4 + 1) * UPXS + base] = t.y;
    uS[(px4 * 4 + 2) * UPXS + base] = t.z;
    uS[(px4 * 4 + 3) * UPXS + base] = t.w;
  }
  __syncthreads();

#pragma unroll
  for (int j = 0; j < 2; ++j) {
    int id = j * 512 + tid;
    if (id < 800) {
      int px = id & 15, sr = id >> 4;
      int s2 = sr / 25, r = sr % 25;
      const float4* xw4 = (const float4*)&xprojw[(s2 * 25 + r) * HEADn];
      float4 w0 = xw4[0], w1 = xw4[1], w2 = xw4[2], w3 = xw4[3];
      float wv[16];
      wv[0]=w0.x; wv[1]=w0.y; wv[2]=w0.z; wv[3]=w0.w;
      wv[4]=w1.x; wv[5]=w1.y; wv[6]=w1.z; wv[7]=w1.w;
      wv[8]=w2.x; wv[9]=w2.y; wv[10]=w2.z; wv[11]=w2.w;
      wv[12]=w3.x; wv[13]=w3.y; wv[14]=w3.z; wv[15]=w3.w;
      int ub = px * UPXS + s2 * USS;
      float acc[12];
#pragma unroll
      for (int cc = 0; cc < 12; ++cc) acc[cc] = 0.f;
#pragma unroll
      for (int dd = 0; dd < HEADn; ++dd) {
        float w = wv[dd];
        int ua = ub + dd * UDS;
#pragma unroll
        for (int cc = 0; cc < 12; ++cc)
          acc[cc] = fmaf(uS[ua + cc], w, acc[cc]);
      }
      float* xp = &xdl[px * XPXS + s2 * XSS + r * 12];
      *(float4*)&xp[0] = make_float4(acc[0], acc[1], acc[2], acc[3]);
      *(float4*)&xp[4] = make_float4(acc[4], acc[5], acc[6], acc[7]);
      *(float4*)&xp[8] = make_float4(acc[8], acc[9], acc[10], acc[11]);
    }
  }
  __syncthreads();

  {
    const int px = p2px, s = p2s, d = p2d;
    const int ub = px * UPXS + s * USS + d * UDS;
    float uvv[12];
#pragma unroll
    for (int cc = 0; cc < 12; ++cc) uvv[cc] = uS[ub + cc];

    const int xb = px * XPXS;
    float dts[12];
    {
      const float4* dr = (const float4*)&xdl[xb + s * XSS];   // r = 0
      float4 q0 = dr[0], q1 = dr[1], q2 = dr[2];
      dts[0]=q0.x; dts[1]=q0.y; dts[2]=q0.z; dts[3]=q0.w;
      dts[4]=q1.x; dts[5]=q1.y; dts[6]=q1.z; dts[7]=q1.w;
      dts[8]=q2.x; dts[9]=q2.y; dts[10]=q2.z; dts[11]=q2.w;
    }
    float dt_s[12], dtu[12];
#pragma unroll
    for (int cc = 0; cc < 12; ++cc) {
      float pre = fmaf(dts[cc], dtw, dtb);
      float v = (pre > 20.f) ? pre : log1pf(expf(pre));       // softplus
      dt_s[cc] = v;
      dtu[cc] = v * uvv[cc];
    }

    float y[12];
#pragma unroll
    for (int cc = 0; cc < 12; ++cc) y[cc] = 0.f;

#pragma unroll
    for (int n = 0; n < Nn; ++n) {
      const float4* Br = (const float4*)&xdl[xb + s * XSS + (1 + n) * 12];
      const float4* Cr = (const float4*)&xdl[xb + (1 - s) * XSS + (13 + n) * 12];
      float4 b0 = Br[0], b1 = Br[1], b2 = Br[2];
      float4 c0 = Cr[0], c1 = Cr[1], c2 = Cr[2];
      float Bv[12], Cv[12];
      Bv[0]=b0.x; Bv[1]=b0.y; Bv[2]=b0.z; Bv[3]=b0.w;
      Bv[4]=b1.x; Bv[5]=b1.y; Bv[6]=b1.z; Bv[7]=b1.w;
      Bv[8]=b2.x; Bv[9]=b2.y; Bv[10]=b2.z; Bv[11]=b2.w;
      Cv[0]=c0.x; Cv[1]=c0.y; Cv[2]=c0.z; Cv[3]=c0.w;
      Cv[4]=c1.x; Cv[5]=c1.y; Cv[6]=c1.z; Cv[7]=c1.w;
      Cv[8]=c2.x; Cv[9]=c2.y; Cv[10]=c2.z; Cv[11]=c2.w;
      float h = 0.f;
      float An = Ar[n];
#pragma unroll
      for (int cc = 0; cc < 12; ++cc) {
        float dA = expf(dt_s[cc] * An);
        h = fmaf(dA, h, dtu[cc] * Bv[cc]);
        y[cc] = fmaf(h, Cv[cc], y[cc]);
      }
    }

#pragma unroll
    for (int cc = 0; cc < 12; ++cc) y[cc] = fmaf(uvv[cc], Dv, y[cc]);

    float mu = 0.f;
#pragma unroll
    for (int cc = 0; cc < 12; ++cc) mu += y[cc];
    mu *= (1.f / CCn);
    float var = 0.f;
#pragma unroll
    for (int cc = 0; cc < 12; ++cc) { float t = y[cc] - mu; var = fmaf(t, t, var); }
    var *= (1.f / CCn);
    float rs = rsqrtf(var + 1e-5f);
    const float* ow = s ? on2w : on1w;
    const float* ob = s ? on2b : on1b;
#pragma unroll
    for (int cc = 0; cc < 12; ++cc)
      uS[ub + cc] = fmaf((y[cc] - mu) * rs, ow[cc], ob[cc]);
  }
  __syncthreads();

#pragma unroll
  for (int i = 0; i < 2; ++i) {
    int id = i * 512 + tid;
    if (id < 768) {
      int px4 = id & 3, ch = (id >> 2) % Cn, ss = id / 384;
      int g = ch >> 2, co = ch & 3;
      const float* ow2 = (ss ? opw1 : opw0) + g * 32 + co * 8;
      float a0 = 0.f, a1 = 0.f, a2 = 0.f, a3 = 0.f;
#pragma unroll
      for (int ci = 0; ci < 8; ++ci) {
        int e = g * 8 + ci;
        int dd = e / 12, cc = e % 12;
        int base = ss * USS + dd * UDS + cc;
        float w = ow2[ci];
        a0 = fmaf(uS[(px4 * 4 + 0) * UPXS + base], w, a0);
        a1 = fmaf(uS[(px4 * 4 + 1) * UPXS + base], w, a1);
        a2 = fmaf(uS[(px4 * 4 + 2) * UPXS + base], w, a2);
        a3 = fmaf(uS[(px4 * 4 + 3) * UPXS + base], w, a3);
      }
      size_t go = (((size_t)ss * Bn + b) * Cn + ch) * HWn + l0 + px4 * 4;
      float4 xrv = *(const float4*)&xr_ws[go];
      *(float4*)&z_ws[go] =
          make_float4(a0 + xrv.x, a1 + xrv.y, a2 + xrv.z, a3 + xrv.w);
    }
  }
}

// ---------------------------------------------------------------------------
// K4 v2: transpose only w1 -> w1t[s][c][o]. (frozen)
// ---------------------------------------------------------------------------
__global__ void k_transpose_w1(
    const float* __restrict__ w1r, const float* __restrict__ w1e,
    float* __restrict__ w1t)
{
  int idx = blockIdx.x * 256 + threadIdx.x;     // 0 .. 73727
  if (idx < 2 * 36864) {
    int which = idx / 36864;
    int r = idx % 36864;
    int c = r / HDn, o = r % HDn;               // dest [c][o]
    const float* src = which ? w1e : w1r;       // src [o][c]
    w1t[idx] = src[o * Cn + c];
  }
}

// ---------------------------------------------------------------------------
// K5 v4: fused MLP — v3 structure + deep unroll for L2-latency hiding.
//  fc1: c-loop unroll 4 -> 192 indep FMA-instrs (384 cyc) per 12-load batch.
//  fc2: o4-loop unroll 2 -> 96 FMA-instrs per 6-load batch.
// Math and summation order identical to v3 (c ascending / o ascending).
// ---------------------------------------------------------------------------
__global__ __launch_bounds__(256, 2) void k_mlp(
    const float* __restrict__ z_all,
    const float* __restrict__ n1w, const float* __restrict__ n1b,
    const float* __restrict__ n2w, const float* __restrict__ n2b,
    const float* __restrict__ w1t_all, const float* __restrict__ b1r,
    const float* __restrict__ b1e,
    const float* __restrict__ w2r_, const float* __restrict__ w2e_,
    const float* __restrict__ b2r, const float* __restrict__ b2e,
    float* __restrict__ out_all)
{
  __shared__ __align__(16) float zn[Cn * 32];   // 12 KB
  __shared__ __align__(16) float hS[HDn * 32];  // 48 KB
  __shared__ float red[2 * 8 * 32];             // 2 KB
  __shared__ float mus[32], rss[32];

  const int s    = blockIdx.y;
  const int tile = blockIdx.x;                 // 0..1023
  const int b    = (tile * 32) >> 14;
  const int l0   = (tile * 32) & (HWn - 1);
  const int tid  = threadIdx.x;

  const float* z   = z_all + ((size_t)s * Bn + b) * Cn * HWn + l0;
  float*       out = (float*)out_all + ((size_t)s * Bn + b) * Cn * HWn + l0;
  const float* nw  = s ? n2w : n1w;
  const float* nb  = s ? n2b : n1b;
  const float* w1t = w1t_all + s * 36864;
  const float* b1  = s ? b1e : b1r;
  const float* w2  = s ? w2e_ : w2r_;          // [96][384] original layout
  const float* b2  = s ? b2e : b2r;

  // ---- phase 0: load z tile + LN ----
  {
    const int px = tid & 31, part = tid >> 5;   // 8 parts x 12 channels
    float psum = 0.f, pss = 0.f;
#pragma unroll
    for (int i = 0; i < 12; ++i) {
      int c = part + 8 * i;
      float v = z[(size_t)c * HWn + px];
      zn[c * 32 + px] = v; psum += v; pss += v * v;
    }
    red[part * 32 + px] = psum;
    red[256 + part * 32 + px] = pss;
    __syncthreads();
    if (tid < 32) {
      float sm = 0.f, sq = 0.f;
#pragma unroll
      for (int p = 0; p < 8; ++p) { sm += red[p * 32 + tid]; sq += red[256 + p * 32 + tid]; }
      float mu = sm * (1.f / Cn);
      float var = sq * (1.f / Cn) - mu * mu;
      mus[tid] = mu; rss[tid] = rsqrtf(var + 1e-6f);
    }
    __syncthreads();
    float mu = mus[px], rs = rss[px];
#pragma unroll
    for (int i = 0; i < 12; ++i) {
      int c = part + 8 * i;
      float v = zn[c * 32 + px];
      zn[c * 32 + px] = fmaf((v - mu) * rs, nw[c], nb[c]);
    }
    __syncthreads();
  }

  const int pg = (tid & 7) << 2;               // pixel base 0,4,...,28

  // ---- phase 1: fc1 + GELU -> hS (12 out x 4 px, unroll 4) ----
  {
    const int og = (tid >> 3) * 12;            // output base 0..372 (48B-aligned)
    float acc[12][4];
#pragma unroll
    for (int j = 0; j < 12; ++j)
#pragma unroll
      for (int i = 0; i < 4; ++i) acc[j][i] = 0.f;

#pragma unroll 4
    for (int c = 0; c < Cn; ++c) {
      float4 xv = *(const float4*)&zn[c * 32 + pg];
      const float4* wr = (const float4*)&w1t[c * HDn + og];
      float4 wq0 = wr[0], wq1 = wr[1], wq2 = wr[2];
      float w[12] = {wq0.x, wq0.y, wq0.z, wq0.w,
                     wq1.x, wq1.y, wq1.z, wq1.w,
                     wq2.x, wq2.y, wq2.z, wq2.w};
#pragma unroll
      for (int j = 0; j < 12; ++j) {
        acc[j][0] = fmaf(xv.x, w[j], acc[j][0]);
        acc[j][1] = fmaf(xv.y, w[j], acc[j][1]);
        acc[j][2] = fmaf(xv.z, w[j], acc[j][2]);
        acc[j][3] = fmaf(xv.w, w[j], acc[j][3]);
      }
    }
#pragma unroll
    for (int j = 0; j < 12; ++j) {
      float bo = b1[og + j];
      float g0 = acc[j][0] + bo, g1 = acc[j][1] + bo;
      float g2 = acc[j][2] + bo, g3 = acc[j][3] + bo;
      g0 = 0.5f * g0 * (1.f + erff(g0 * 0.70710678118654752f));
      g1 = 0.5f * g1 * (1.f + erff(g1 * 0.70710678118654752f));
      g2 = 0.5f * g2 * (1.f + erff(g2 * 0.70710678118654752f));
      g3 = 0.5f * g3 * (1.f + erff(g3 * 0.70710678118654752f));
      *(float4*)&hS[(og + j) * 32 + pg] = make_float4(g0, g1, g2, g3);
    }
  }
  __syncthreads();

  // ---- phase 2: fc2 + bias + residual -> out (3 ch x 4 px, unroll 2) ----
  {
    const int cg = (tid >> 3) * 3;             // out-channel base 0..93
    float a0[4], a1[4], a2[4];
#pragma unroll
    for (int i = 0; i < 4; ++i) { a0[i] = 0.f; a1[i] = 0.f; a2[i] = 0.f; }

    const float* w2s0 = w2 + (size_t)(cg + 0) * HDn;
    const float* w2s1 = w2 + (size_t)(cg + 1) * HDn;
    const float* w2s2 = w2 + (size_t)(cg + 2) * HDn;

#pragma unroll 2
    for (int o4 = 0; o4 < HDn; o4 += 4) {
      float4 h0 = *(const float4*)&hS[(o4 + 0) * 32 + pg];
      float4 h1 = *(const float4*)&hS[(o4 + 1) * 32 + pg];
      float4 h2 = *(const float4*)&hS[(o4 + 2) * 32 + pg];
      float4 h3 = *(const float4*)&hS[(o4 + 3) * 32 + pg];
      float4 wA = *(const float4*)&w2s0[o4];
      float4 wB = *(const float4*)&w2s1[o4];
      float4 wC = *(const float4*)&w2s2[o4];
      // o ascending within each accumulator (same order as v3)
      a0[0] = fmaf(h3.x, wA.w, fmaf(h2.x, wA.z, fmaf(h1.x, wA.y, fmaf(h0.x, wA.x, a0[0]))));
      a0[1] = fmaf(h3.y, wA.w, fmaf(h2.y, wA.z, fmaf(h1.y, wA.y, fmaf(h0.y, wA.x, a0[1]))));
      a0[2] = fmaf(h3.z, wA.w, fmaf(h2.z, wA.z, fmaf(h1.z, wA.y, fmaf(h0.z, wA.x, a0[2]))));
      a0[3] = fmaf(h3.w, wA.w, fmaf(h2.w, wA.z, fmaf(h1.w, wA.y, fmaf(h0.w, wA.x, a0[3]))));
      a1[0] = fmaf(h3.x, wB.w, fmaf(h2.x, wB.z, fmaf(h1.x, wB.y, fmaf(h0.x, wB.x, a1[0]))));
      a1[1] = fmaf(h3.y, wB.w, fmaf(h2.y, wB.z, fmaf(h1.y, wB.y, fmaf(h0.y, wB.x, a1[1]))));
      a1[2] = fmaf(h3.z, wB.w, fmaf(h2.z, wB.z, fmaf(h1.z, wB.y, fmaf(h0.z, wB.x, a1[2]))));
      a1[3] = fmaf(h3.w, wB.w, fmaf(h2.w, wB.z, fmaf(h1.w, wB.y, fmaf(h0.w, wB.x, a1[3]))));
      a2[0] = fmaf(h3.x, wC.w, fmaf(h2.x, wC.z, fmaf(h1.x, wC.y, fmaf(h0.x, wC.x, a2[0]))));
      a2[1] = fmaf(h3.y, wC.w, fmaf(h2.y, wC.z, fmaf(h1.y, wC.y, fmaf(h0.y, wC.x, a2[1]))));
      a2[2] = fmaf(h3.z, wC.w, fmaf(h2.z, wC.z, fmaf(h1.z, wC.y, fmaf(h0.z, wC.x, a2[2]))));
      a2[3] = fmaf(h3.w, wC.w, fmaf(h2.w, wC.z, fmaf(h1.w, wC.y, fmaf(h0.w, wC.x, a2[3]))));
    }
#pragma unroll
    for (int k = 0; k < 3; ++k) {
      int c = cg + k;
      float bk = b2[c];
      const float* ak = (k == 0) ? a0 : (k == 1) ? a1 : a2;
#pragma unroll
      for (int i = 0; i < 4; ++i) {
        size_t off = (size_t)c * HWn + pg + i;
        out[off] = ak[i] + bk + z[off];
      }
    }
  }
}

// ---------------------------------------------------------------------------
extern "C" void kernel_launch(void* const* d_in, const int* in_sizes, int n_in,
                              void* d_out, int out_size, void* d_ws, size_t ws_size,
                              hipStream_t stream)
{
  const float* x_rgb = (const float*)d_in[0];
  const float* x_e   = (const float*)d_in[1];
  const float* in1_w = (const float*)d_in[2];
  const float* in1_b = (const float*)d_in[3];
  const float* in2_w = (const float*)d_in[4];
  const float* in2_b = (const float*)d_in[5];
  const float* ipw0  = (const float*)d_in[6];
  const float* ipw1  = (const float*)d_in[7];
  const float* cw0   = (const float*)d_in[8];
  const float* cb0   = (const float*)d_in[9];
  const float* cw1   = (const float*)d_in[10];
  const float* cb1   = (const float*)d_in[11];
  const float* xprojw  = (const float*)d_in[12];
  const float* dtprojw = (const float*)d_in[13];
  const float* dtprojb = (const float*)d_in[14];
  const float* A_logs  = (const float*)d_in[15];
  const float* Ds      = (const float*)d_in[16];
  const float* on1w  = (const float*)d_in[17];
  const float* on1b  = (const float*)d_in[18];
  const float* on2w  = (const float*)d_in[19];
  const float* on2b  = (const float*)d_in[20];
  const float* opw0  = (const float*)d_in[21];
  const float* opw1  = (const float*)d_in[22];
  const float* n1w   = (const float*)d_in[23];
  const float* n1b   = (const float*)d_in[24];
  const float* n2w   = (const float*)d_in[25];
  const float* n2b   = (const float*)d_in[26];
  const float* w1r   = (const float*)d_in[27];
  const float* b1r   = (const float*)d_in[28];
  const float* w2r   = (const float*)d_in[29];
  const float* b2r   = (const float*)d_in[30];
  const float* w1e   = (const float*)d_in[31];
  const float* b1e   = (const float*)d_in[32];
  const float* w2e   = (const float*)d_in[33];
  const float* b2e   = (const float*)d_in[34];

  float* ws  = (float*)d_ws;
  float* xr  = ws;                              // 2*B*C*HW  = 6291456 f
  float* vz  = ws + (size_t)6291456;            // 2*B*E*HW  = 12582912 f (v, later z)
  float* ut  = ws + (size_t)18874368;           // 2*B*E*HW  = 12582912 f (u; reused for w1t)
  float* w1t = ut;                              // 2*36864 f (after k_ssm consumed u)

  dim3 b256(256);

  k_ln_inproj<<<dim3(512, 2), b256, 0, stream>>>(
      x_rgb, x_e, in1_w, in1_b, in2_w, in2_b, ipw0, ipw1, xr, vz);

  k_dwconv_silu<<<dim3(64, En, 4), b256, 0, stream>>>(
      vz, cw0, cb0, cw1, cb1, ut);

  k_ssm<<<dim3(2048), dim3(512), 0, stream>>>(
      ut, xr, vz, xprojw, dtprojw, dtprojb, A_logs, Ds,
      on1w, on1b, on2w, on2b, opw0, opw1);

  // u (in ut) is dead now; reuse its space for the transposed w1.
  k_transpose_w1<<<dim3(288), b256, 0, stream>>>(w1r, w1e, w1t);

  k_mlp<<<dim3(1024, 2), b256, 0, stream>>>(
      vz, n1w, n1b, n2w, n2b, w1t, b1r, b1e, w2r, w2e, b2r, b2e, (float*)d_out);
}